// Round 4
// baseline (307.670 us; speedup 1.0000x reference)
//
#include <hip/hip_runtime.h>

#define NN 50000
#define NP 25000
#define NE 800000
#define DD 64
#define NL 4

// ---- helpers ------------------------------------------------------------

__device__ __forceinline__ ushort f2bf(float f) {
    unsigned u = __float_as_uint(f);
    unsigned r = (u + 0x7fffu + ((u >> 16) & 1u)) >> 16;   // RNE
    return (ushort)r;
}

__device__ __forceinline__ float4 ld_bf16x4(const uint2* p) {
    uint2 q = *p;
    float4 r;
    r.x = __uint_as_float(q.x << 16);
    r.y = __uint_as_float(q.x & 0xffff0000u);
    r.z = __uint_as_float(q.y << 16);
    r.w = __uint_as_float(q.y & 0xffff0000u);
    return r;
}

// ---- CSR build ----------------------------------------------------------

__global__ void count_edges_k(const int* __restrict__ dst, int* __restrict__ cnt, int E) {
    int e = blockIdx.x * 256 + threadIdx.x;
    if (e < E) atomicAdd(&cnt[dst[e]], 1);
}

__global__ void scan_local_k(const int* __restrict__ cnt, int* __restrict__ rowptr,
                             int* __restrict__ bsum, int n) {
    __shared__ int tmp[1024];
    int t = threadIdx.x;
    int i = blockIdx.x * 1024 + t;
    int v = (i < n) ? cnt[i] : 0;
    tmp[t] = v;
    __syncthreads();
    for (int off = 1; off < 1024; off <<= 1) {
        int a = (t >= off) ? tmp[t - off] : 0;
        __syncthreads();
        tmp[t] += a;
        __syncthreads();
    }
    if (i < n) rowptr[i] = tmp[t] - v;      // block-local exclusive scan
    if (t == 1023) bsum[blockIdx.x] = tmp[1023];
}

__global__ void scan_sums_k(int* bsum, int nb, int* rowptr, int n) {
    if (threadIdx.x == 0 && blockIdx.x == 0) {
        int run = 0;
        for (int b = 0; b < nb; ++b) { int s = bsum[b]; bsum[b] = run; run += s; }
        rowptr[n] = run;
    }
}

__global__ void finalize_k(int* __restrict__ rowptr, const int* __restrict__ bsum,
                           const int* __restrict__ cnt, float* __restrict__ dinv,
                           int* __restrict__ cursor, int n) {
    int i = blockIdx.x * 1024 + threadIdx.x;
    if (i < n) {
        rowptr[i] += bsum[blockIdx.x];
        dinv[i] = rsqrtf((float)(cnt[i] + 1));   // +1 self loop; deg >= 1 always
        cursor[i] = 0;
    }
}

__global__ void fill_csr_k(const int* __restrict__ src, const int* __restrict__ dst,
                           const int* __restrict__ rowptr, int* __restrict__ cursor,
                           const float* __restrict__ dinv, int2* __restrict__ csr_sw, int E) {
    int e = blockIdx.x * 256 + threadIdx.x;
    if (e >= E) return;
    int s = src[e], d = dst[e];
    int p = rowptr[d] + atomicAdd(&cursor[d], 1);
    csr_sw[p] = make_int2(s, __float_as_int(dinv[s] * dinv[d]));
}

// ---- unpool scatter (f32 -> bf16 rows) ----------------------------------

__global__ void scatter_x_k(const float4* __restrict__ x4, const int* __restrict__ idx,
                            ushort4* __restrict__ c0) {
    int i = blockIdx.x * 256 + threadIdx.x;   // NP*16 quads
    if (i >= NP * 16) return;
    int row = i >> 4, q = i & 15;
    float4 v = x4[i];
    ushort4 o;
    o.x = f2bf(v.x); o.y = f2bf(v.y); o.z = f2bf(v.z); o.w = f2bf(v.w);
    c0[(size_t)idx[row] * 16 + q] = o;
}

// ---- fused: gather-aggregate + matvec(W) + bias + LN + LeakyReLU --------
// z = A_hat * cur  (gather bf16 rows; 4 groups x 16 lanes, 4x unroll)
// y = z @ W + b    (split-k matvec: group g covers k in [16g,16g+16))
// next = leaky(LN(y))  stored bf16
__global__ void agg_mm_ln_k(const uint2* __restrict__ cur2, const int* __restrict__ rowptr,
                            const int2* __restrict__ csr_sw, const float* __restrict__ dinv,
                            const float* __restrict__ W, const float4* __restrict__ bias4,
                            const float4* __restrict__ gamma4, const float4* __restrict__ beta4,
                            ushort4* __restrict__ next) {
    int tid = threadIdx.x;
    int lane = tid & 63;
    int g = lane >> 4;          // edge-slot / k-range group 0..3
    int fl = lane & 15;         // feature quad 0..15
    int v = blockIdx.x * 4 + (tid >> 6);
    float dv = dinv[v];
    int jb = rowptr[v], je = rowptr[v + 1];
    float4 acc = make_float4(0.f, 0.f, 0.f, 0.f);
    if (g == 0) {                               // self loop, added once
        float4 r = ld_bf16x4(cur2 + (size_t)v * 16 + fl);
        float s = dv * dv;
        acc.x = s * r.x; acc.y = s * r.y; acc.z = s * r.z; acc.w = s * r.w;
    }
    for (int j = jb + g; j < je; j += 16) {
        int ja = j + 4, jb2 = j + 8, jc = j + 12;
        int2 s0 = csr_sw[j];
        int2 s1 = csr_sw[min(ja, je - 1)];
        int2 s2 = csr_sw[min(jb2, je - 1)];
        int2 s3 = csr_sw[min(jc, je - 1)];
        float w0 = __int_as_float(s0.y);
        float w1 = (ja  < je) ? __int_as_float(s1.y) : 0.f;
        float w2 = (jb2 < je) ? __int_as_float(s2.y) : 0.f;
        float w3 = (jc  < je) ? __int_as_float(s3.y) : 0.f;
        float4 r0 = ld_bf16x4(cur2 + (size_t)s0.x * 16 + fl);
        float4 r1 = ld_bf16x4(cur2 + (size_t)s1.x * 16 + fl);
        float4 r2 = ld_bf16x4(cur2 + (size_t)s2.x * 16 + fl);
        float4 r3 = ld_bf16x4(cur2 + (size_t)s3.x * 16 + fl);
        acc.x += w0 * r0.x + w1 * r1.x + w2 * r2.x + w3 * r3.x;
        acc.y += w0 * r0.y + w1 * r1.y + w2 * r2.y + w3 * r3.y;
        acc.z += w0 * r0.z + w1 * r1.z + w2 * r2.z + w3 * r3.z;
        acc.w += w0 * r0.w + w1 * r1.w + w2 * r2.w + w3 * r3.w;
    }
    // combine the 4 edge-slot groups -> every lane holds z[4fl..4fl+3]
#pragma unroll
    for (int o = 16; o <= 32; o <<= 1) {
        acc.x += __shfl_xor(acc.x, o);
        acc.y += __shfl_xor(acc.y, o);
        acc.z += __shfl_xor(acc.z, o);
        acc.w += __shfl_xor(acc.w, o);
    }
    // split-k matvec: lane (g,fl) computes cols 4fl..4fl+3 over k=16g..16g+15
    float4 y = make_float4(0.f, 0.f, 0.f, 0.f);
    const float* Wp = W + (size_t)(16 * g) * 64 + 4 * fl;
#pragma unroll
    for (int j = 0; j < 16; ++j) {
        int holder = 20 * g + (j >> 2);           // lane holding z[16g+j]
        float zk;
        if ((j & 3) == 0)      zk = __shfl(acc.x, holder);
        else if ((j & 3) == 1) zk = __shfl(acc.y, holder);
        else if ((j & 3) == 2) zk = __shfl(acc.z, holder);
        else                   zk = __shfl(acc.w, holder);
        float4 w = *(const float4*)(Wp + j * 64);
        y.x += zk * w.x; y.y += zk * w.y; y.z += zk * w.z; y.w += zk * w.w;
    }
    // combine k-partials across groups -> full y quad in every lane
#pragma unroll
    for (int o = 16; o <= 32; o <<= 1) {
        y.x += __shfl_xor(y.x, o);
        y.y += __shfl_xor(y.y, o);
        y.z += __shfl_xor(y.z, o);
        y.w += __shfl_xor(y.w, o);
    }
    float4 b = bias4[fl];
    y.x += b.x; y.y += b.y; y.z += b.z; y.w += b.w;
    // LayerNorm over 64 features (16 lanes x 4 comps; groups hold copies)
    float s = y.x + y.y + y.z + y.w;
#pragma unroll
    for (int o = 1; o <= 8; o <<= 1) s += __shfl_xor(s, o);
    float mu = s * (1.0f / 64.0f);
    float4 xc = make_float4(y.x - mu, y.y - mu, y.z - mu, y.w - mu);
    float q = xc.x * xc.x + xc.y * xc.y + xc.z * xc.z + xc.w * xc.w;
#pragma unroll
    for (int o = 1; o <= 8; o <<= 1) q += __shfl_xor(q, o);
    float rs = rsqrtf(q * (1.0f / 64.0f) + 1e-5f);
    float4 gm = gamma4[fl], bt = beta4[fl];
    float4 yy = make_float4(xc.x * rs * gm.x + bt.x, xc.y * rs * gm.y + bt.y,
                            xc.z * rs * gm.z + bt.z, xc.w * rs * gm.w + bt.w);
    float4 act = make_float4(yy.x > 0.f ? yy.x : 0.01f * yy.x,
                             yy.y > 0.f ? yy.y : 0.01f * yy.y,
                             yy.z > 0.f ? yy.z : 0.01f * yy.z,
                             yy.w > 0.f ? yy.w : 0.01f * yy.w);
    if (g == 0) {                       // 16 lanes write the 128B bf16 row
        ushort4 o;
        o.x = f2bf(act.x); o.y = f2bf(act.y); o.z = f2bf(act.z); o.w = f2bf(act.w);
        next[(size_t)v * 16 + fl] = o;
    }
}

// ---- final: h = 0.5*(act1+act2+act3+act4) -------------------------------

__global__ void final_h_k(const uint2* __restrict__ c1, const uint2* __restrict__ c2,
                          const uint2* __restrict__ c3, const uint2* __restrict__ c4,
                          float4* __restrict__ out) {
    int i = blockIdx.x * 256 + threadIdx.x;   // NN*16 quads
    if (i >= NN * 16) return;
    float4 a = ld_bf16x4(c1 + i);
    float4 b = ld_bf16x4(c2 + i);
    float4 c = ld_bf16x4(c3 + i);
    float4 d = ld_bf16x4(c4 + i);
    float4 o;
    o.x = 0.5f * (a.x + b.x + c.x + d.x);
    o.y = 0.5f * (a.y + b.y + c.y + d.y);
    o.z = 0.5f * (a.z + b.z + c.z + d.z);
    o.w = 0.5f * (a.w + b.w + c.w + d.w);
    out[i] = o;
}

// ---- launch -------------------------------------------------------------

extern "C" void kernel_launch(void* const* d_in, const int* in_sizes, int n_in,
                              void* d_out, int out_size, void* d_ws, size_t ws_size,
                              hipStream_t stream) {
    const float* x      = (const float*)d_in[0];
    const int*   ei     = (const int*)d_in[1];
    const int*   src    = ei;
    const int*   dst    = ei + NE;
    const int*   idx    = (const int*)d_in[2];
    const float* Ws     = (const float*)d_in[3];
    const float* bs     = (const float*)d_in[4];
    const float* gammas = (const float*)d_in[5];
    const float* betas  = (const float*)d_in[6];
    float* out = (float*)d_out;

    char* w = (char*)d_ws;
    auto alloc = [&](size_t bytes) -> char* {
        char* p = w;
        w += (bytes + 255) & ~(size_t)255;
        return p;
    };
    ushort* c[NL + 1];
    for (int l = 0; l <= NL; ++l) c[l] = (ushort*)alloc((size_t)NN * 64 * 2);
    int*   cnt    = (int*)alloc((size_t)NN * 4);
    int*   rowptr = (int*)alloc((size_t)(NN + 1) * 4);
    int*   cursor = (int*)alloc((size_t)NN * 4);
    float* dinv   = (float*)alloc((size_t)NN * 4);
    int*   bsum   = (int*)alloc(64 * 4);
    int2*  csr_sw = (int2*)alloc((size_t)NE * 8);

    hipMemsetAsync(cnt, 0, (size_t)NN * 4, stream);
    hipMemsetAsync(c[0], 0, (size_t)NN * 64 * 2, stream);

    count_edges_k<<<(NE + 255) / 256, 256, 0, stream>>>(dst, cnt, NE);
    int nb = (NN + 1023) / 1024;   // 49
    scan_local_k<<<nb, 1024, 0, stream>>>(cnt, rowptr, bsum, NN);
    scan_sums_k<<<1, 64, 0, stream>>>(bsum, nb, rowptr, NN);
    finalize_k<<<nb, 1024, 0, stream>>>(rowptr, bsum, cnt, dinv, cursor, NN);
    fill_csr_k<<<(NE + 255) / 256, 256, 0, stream>>>(src, dst, rowptr, cursor, dinv,
                                                     csr_sw, NE);
    scatter_x_k<<<(NP * 16 + 255) / 256, 256, 0, stream>>>((const float4*)x, idx,
                                                           (ushort4*)c[0]);

    for (int l = 0; l < NL; ++l) {
        agg_mm_ln_k<<<NN / 4, 256, 0, stream>>>((const uint2*)c[l], rowptr, csr_sw, dinv,
                                                Ws + (size_t)l * 64 * 64,
                                                (const float4*)(bs + l * 64),
                                                (const float4*)(gammas + l * 64),
                                                (const float4*)(betas + l * 64),
                                                (ushort4*)c[l + 1]);
    }
    final_h_k<<<(NN * 16 + 255) / 256, 256, 0, stream>>>((const uint2*)c[1], (const uint2*)c[2],
                                                         (const uint2*)c[3], (const uint2*)c[4],
                                                         (float4*)out);
}

// Round 5
// 265.033 us; speedup vs baseline: 1.1609x; 1.1609x over previous
//
#include <hip/hip_runtime.h>

#define NN 50000
#define NP 25000
#define NE 800000
#define DD 64
#define NL 4

// ---- helpers ------------------------------------------------------------

__device__ __forceinline__ ushort f2bf(float f) {
    unsigned u = __float_as_uint(f);
    unsigned r = (u + 0x7fffu + ((u >> 16) & 1u)) >> 16;   // RNE
    return (ushort)r;
}

__device__ __forceinline__ float4 bf4_to_f4(uint2 q) {
    float4 r;
    r.x = __uint_as_float(q.x << 16);
    r.y = __uint_as_float(q.x & 0xffff0000u);
    r.z = __uint_as_float(q.y << 16);
    r.w = __uint_as_float(q.y & 0xffff0000u);
    return r;
}

__device__ __forceinline__ float4 ld_bf16x4(const uint2* p) { return bf4_to_f4(*p); }

// ---- CSR build ----------------------------------------------------------

__global__ void count_edges_k(const int* __restrict__ dst, int* __restrict__ cnt, int E) {
    int e = blockIdx.x * 256 + threadIdx.x;
    if (e < E) atomicAdd(&cnt[dst[e]], 1);
}

__global__ void scan_local_k(const int* __restrict__ cnt, int* __restrict__ rowptr,
                             int* __restrict__ bsum, int n) {
    __shared__ int tmp[1024];
    int t = threadIdx.x;
    int i = blockIdx.x * 1024 + t;
    int v = (i < n) ? cnt[i] : 0;
    tmp[t] = v;
    __syncthreads();
    for (int off = 1; off < 1024; off <<= 1) {
        int a = (t >= off) ? tmp[t - off] : 0;
        __syncthreads();
        tmp[t] += a;
        __syncthreads();
    }
    if (i < n) rowptr[i] = tmp[t] - v;      // block-local exclusive scan
    if (t == 1023) bsum[blockIdx.x] = tmp[1023];
}

__global__ void scan_sums_k(int* bsum, int nb, int* rowptr, int n) {
    if (threadIdx.x == 0 && blockIdx.x == 0) {
        int run = 0;
        for (int b = 0; b < nb; ++b) { int s = bsum[b]; bsum[b] = run; run += s; }
        rowptr[n] = run;
    }
}

__global__ void finalize_k(int* __restrict__ rowptr, const int* __restrict__ bsum,
                           const int* __restrict__ cnt, float* __restrict__ dinv,
                           int* __restrict__ cursor, int n) {
    int i = blockIdx.x * 1024 + threadIdx.x;
    if (i < n) {
        rowptr[i] += bsum[blockIdx.x];
        dinv[i] = rsqrtf((float)(cnt[i] + 1));   // +1 self loop; deg >= 1 always
        cursor[i] = 0;
    }
}

__global__ void fill_csr_k(const int* __restrict__ src, const int* __restrict__ dst,
                           const int* __restrict__ rowptr, int* __restrict__ cursor,
                           const float* __restrict__ dinv, int2* __restrict__ csr_sw, int E) {
    int e = blockIdx.x * 256 + threadIdx.x;
    if (e >= E) return;
    int s = src[e], d = dst[e];
    int p = rowptr[d] + atomicAdd(&cursor[d], 1);
    csr_sw[p] = make_int2(s, __float_as_int(dinv[s] * dinv[d]));
}

// ---- unpool scatter (f32 -> bf16 rows) ----------------------------------

__global__ void scatter_x_k(const float4* __restrict__ x4, const int* __restrict__ idx,
                            ushort4* __restrict__ c0) {
    int i = blockIdx.x * 256 + threadIdx.x;   // NP*16 quads
    if (i >= NP * 16) return;
    int row = i >> 4, q = i & 15;
    float4 v = x4[i];
    ushort4 o;
    o.x = f2bf(v.x); o.y = f2bf(v.y); o.z = f2bf(v.z); o.w = f2bf(v.w);
    c0[(size_t)idx[row] * 16 + q] = o;
}

// ---- GEMM: xw_bf16[50000x64] = cur_bf16[50000x64] @ W[64x64] ------------

__global__ void gemm64_k(const uint2* __restrict__ in2, const float* __restrict__ W,
                         ushort* __restrict__ out) {
    __shared__ float sW[64][64];     // 16 KB
    __shared__ float srow[16][64];   // 4 KB
    int t = threadIdx.x;             // 256 threads
    const float4* W4 = (const float4*)W;
    float4* sW4 = (float4*)sW;
#pragma unroll
    for (int j = 0; j < 4; ++j) sW4[t + 256 * j] = W4[t + 256 * j];
    int r0 = blockIdx.x * 16;
    // stage 16 bf16 rows as f32: thread t covers row t>>4, cols 4*(t&15)..+3
    float4 val = bf4_to_f4(in2[(size_t)r0 * 16 + t]);
    *(float4*)&srow[t >> 4][4 * (t & 15)] = val;
    __syncthreads();
    int r = t >> 4;            // 0..15
    int c4 = (t & 15) * 4;     // 0,4,...,60
    float ax = 0.f, ay = 0.f, az = 0.f, aw = 0.f;
#pragma unroll
    for (int k = 0; k < 64; ++k) {
        float a = srow[r][k];
        float4 w = *(const float4*)&sW[k][c4];
        ax += a * w.x; ay += a * w.y; az += a * w.z; aw += a * w.w;
    }
    ushort4 o;
    o.x = f2bf(ax); o.y = f2bf(ay); o.z = f2bf(az); o.w = f2bf(aw);
    *(ushort4*)&out[(size_t)(r0 + r) * 64 + c4] = o;
}

// ---- fused: aggregate(bf16 gather) + bias + LN + LeakyReLU --------------
// 4 nodes per wave: each 16-lane quarter owns one node (no cross-quarter
// shuffles). Lane fl holds feature quad 4fl..4fl+3. Edge loop 8-deep
// unrolled -> 32 gathers in flight per wave. Only 8 DS ops per node (LN).

__global__ void agg_ln_k(const uint2* __restrict__ xw2, const int* __restrict__ rowptr,
                         const int2* __restrict__ csr_sw, const float* __restrict__ dinv,
                         const float4* __restrict__ bias4, const float4* __restrict__ gamma4,
                         const float4* __restrict__ beta4, ushort4* __restrict__ next) {
    int tid = threadIdx.x;
    int fl = tid & 15;                      // feature quad 0..15
    int v = blockIdx.x * 16 + (tid >> 4);   // NN % 16 == 0
    float dv = dinv[v];
    int jb = rowptr[v], je = rowptr[v + 1];
    float4 acc;
    {
        float4 r = ld_bf16x4(xw2 + (size_t)v * 16 + fl);   // self loop
        float s = dv * dv;
        acc.x = s * r.x; acc.y = s * r.y; acc.z = s * r.z; acc.w = s * r.w;
    }
    for (int j = jb; j < je; j += 8) {
        int2 s0 = csr_sw[j];
        int2 s1 = csr_sw[min(j + 1, je - 1)];
        int2 s2 = csr_sw[min(j + 2, je - 1)];
        int2 s3 = csr_sw[min(j + 3, je - 1)];
        int2 s4 = csr_sw[min(j + 4, je - 1)];
        int2 s5 = csr_sw[min(j + 5, je - 1)];
        int2 s6 = csr_sw[min(j + 6, je - 1)];
        int2 s7 = csr_sw[min(j + 7, je - 1)];
        float w0 = __int_as_float(s0.y);
        float w1 = (j + 1 < je) ? __int_as_float(s1.y) : 0.f;
        float w2 = (j + 2 < je) ? __int_as_float(s2.y) : 0.f;
        float w3 = (j + 3 < je) ? __int_as_float(s3.y) : 0.f;
        float w4 = (j + 4 < je) ? __int_as_float(s4.y) : 0.f;
        float w5 = (j + 5 < je) ? __int_as_float(s5.y) : 0.f;
        float w6 = (j + 6 < je) ? __int_as_float(s6.y) : 0.f;
        float w7 = (j + 7 < je) ? __int_as_float(s7.y) : 0.f;
        float4 r0 = ld_bf16x4(xw2 + (size_t)s0.x * 16 + fl);
        float4 r1 = ld_bf16x4(xw2 + (size_t)s1.x * 16 + fl);
        float4 r2 = ld_bf16x4(xw2 + (size_t)s2.x * 16 + fl);
        float4 r3 = ld_bf16x4(xw2 + (size_t)s3.x * 16 + fl);
        float4 r4 = ld_bf16x4(xw2 + (size_t)s4.x * 16 + fl);
        float4 r5 = ld_bf16x4(xw2 + (size_t)s5.x * 16 + fl);
        float4 r6 = ld_bf16x4(xw2 + (size_t)s6.x * 16 + fl);
        float4 r7 = ld_bf16x4(xw2 + (size_t)s7.x * 16 + fl);
        acc.x += w0 * r0.x + w1 * r1.x + w2 * r2.x + w3 * r3.x
               + w4 * r4.x + w5 * r5.x + w6 * r6.x + w7 * r7.x;
        acc.y += w0 * r0.y + w1 * r1.y + w2 * r2.y + w3 * r3.y
               + w4 * r4.y + w5 * r5.y + w6 * r6.y + w7 * r7.y;
        acc.z += w0 * r0.z + w1 * r1.z + w2 * r2.z + w3 * r3.z
               + w4 * r4.z + w5 * r5.z + w6 * r6.z + w7 * r7.z;
        acc.w += w0 * r0.w + w1 * r1.w + w2 * r2.w + w3 * r3.w
               + w4 * r4.w + w5 * r5.w + w6 * r6.w + w7 * r7.w;
    }
    float4 b = bias4[fl];
    acc.x += b.x; acc.y += b.y; acc.z += b.z; acc.w += b.w;
    // LayerNorm over 64 features within the 16-lane quarter
    float s = acc.x + acc.y + acc.z + acc.w;
#pragma unroll
    for (int o = 1; o <= 8; o <<= 1) s += __shfl_xor(s, o);
    float mu = s * (1.0f / 64.0f);
    float4 xc = make_float4(acc.x - mu, acc.y - mu, acc.z - mu, acc.w - mu);
    float q = xc.x * xc.x + xc.y * xc.y + xc.z * xc.z + xc.w * xc.w;
#pragma unroll
    for (int o = 1; o <= 8; o <<= 1) q += __shfl_xor(q, o);
    float rs = rsqrtf(q * (1.0f / 64.0f) + 1e-5f);
    float4 gm = gamma4[fl], bt = beta4[fl];
    float4 y = make_float4(xc.x * rs * gm.x + bt.x, xc.y * rs * gm.y + bt.y,
                           xc.z * rs * gm.z + bt.z, xc.w * rs * gm.w + bt.w);
    float4 act = make_float4(y.x > 0.f ? y.x : 0.01f * y.x,
                             y.y > 0.f ? y.y : 0.01f * y.y,
                             y.z > 0.f ? y.z : 0.01f * y.z,
                             y.w > 0.f ? y.w : 0.01f * y.w);
    ushort4 o;
    o.x = f2bf(act.x); o.y = f2bf(act.y); o.z = f2bf(act.z); o.w = f2bf(act.w);
    next[(size_t)v * 16 + fl] = o;
}

// ---- final: h = 0.5*(act1+act2+act3+act4) -------------------------------

__global__ void final_h_k(const uint2* __restrict__ c1, const uint2* __restrict__ c2,
                          const uint2* __restrict__ c3, const uint2* __restrict__ c4,
                          float4* __restrict__ out) {
    int i = blockIdx.x * 256 + threadIdx.x;   // NN*16 quads
    if (i >= NN * 16) return;
    float4 a = ld_bf16x4(c1 + i);
    float4 b = ld_bf16x4(c2 + i);
    float4 c = ld_bf16x4(c3 + i);
    float4 d = ld_bf16x4(c4 + i);
    float4 o;
    o.x = 0.5f * (a.x + b.x + c.x + d.x);
    o.y = 0.5f * (a.y + b.y + c.y + d.y);
    o.z = 0.5f * (a.z + b.z + c.z + d.z);
    o.w = 0.5f * (a.w + b.w + c.w + d.w);
    out[i] = o;
}

// ---- launch -------------------------------------------------------------

extern "C" void kernel_launch(void* const* d_in, const int* in_sizes, int n_in,
                              void* d_out, int out_size, void* d_ws, size_t ws_size,
                              hipStream_t stream) {
    const float* x      = (const float*)d_in[0];
    const int*   ei     = (const int*)d_in[1];
    const int*   src    = ei;
    const int*   dst    = ei + NE;
    const int*   idx    = (const int*)d_in[2];
    const float* Ws     = (const float*)d_in[3];
    const float* bs     = (const float*)d_in[4];
    const float* gammas = (const float*)d_in[5];
    const float* betas  = (const float*)d_in[6];
    float* out = (float*)d_out;

    char* w = (char*)d_ws;
    auto alloc = [&](size_t bytes) -> char* {
        char* p = w;
        w += (bytes + 255) & ~(size_t)255;
        return p;
    };
    ushort* c[NL + 1];
    for (int l = 0; l <= NL; ++l) c[l] = (ushort*)alloc((size_t)NN * 64 * 2);
    ushort* xw    = (ushort*)alloc((size_t)NN * 64 * 2);
    int*   cnt    = (int*)alloc((size_t)NN * 4);
    int*   rowptr = (int*)alloc((size_t)(NN + 1) * 4);
    int*   cursor = (int*)alloc((size_t)NN * 4);
    float* dinv   = (float*)alloc((size_t)NN * 4);
    int*   bsum   = (int*)alloc(64 * 4);
    int2*  csr_sw = (int2*)alloc((size_t)NE * 8);

    hipMemsetAsync(cnt, 0, (size_t)NN * 4, stream);
    hipMemsetAsync(c[0], 0, (size_t)NN * 64 * 2, stream);

    count_edges_k<<<(NE + 255) / 256, 256, 0, stream>>>(dst, cnt, NE);
    int nb = (NN + 1023) / 1024;   // 49
    scan_local_k<<<nb, 1024, 0, stream>>>(cnt, rowptr, bsum, NN);
    scan_sums_k<<<1, 64, 0, stream>>>(bsum, nb, rowptr, NN);
    finalize_k<<<nb, 1024, 0, stream>>>(rowptr, bsum, cnt, dinv, cursor, NN);
    fill_csr_k<<<(NE + 255) / 256, 256, 0, stream>>>(src, dst, rowptr, cursor, dinv,
                                                     csr_sw, NE);
    scatter_x_k<<<(NP * 16 + 255) / 256, 256, 0, stream>>>((const float4*)x, idx,
                                                           (ushort4*)c[0]);

    for (int l = 0; l < NL; ++l) {
        gemm64_k<<<NN / 16, 256, 0, stream>>>((const uint2*)c[l], Ws + (size_t)l * 64 * 64,
                                              xw);
        agg_ln_k<<<NN / 16, 256, 0, stream>>>((const uint2*)xw, rowptr, csr_sw, dinv,
                                              (const float4*)(bs + l * 64),
                                              (const float4*)(gammas + l * 64),
                                              (const float4*)(betas + l * 64),
                                              (ushort4*)c[l + 1]);
    }
    final_h_k<<<(NN * 16 + 255) / 256, 256, 0, stream>>>((const uint2*)c[1], (const uint2*)c[2],
                                                         (const uint2*)c[3], (const uint2*)c[4],
                                                         (float4*)out);
}

// Round 6
// 235.503 us; speedup vs baseline: 1.3064x; 1.1254x over previous
//
#include <hip/hip_runtime.h>

#define NN 50000
#define NP 25000
#define NE 800000
#define DD 64
#define NL 4

// ---- helpers ------------------------------------------------------------

__device__ __forceinline__ ushort f2bf(float f) {
    unsigned u = __float_as_uint(f);
    unsigned r = (u + 0x7fffu + ((u >> 16) & 1u)) >> 16;   // RNE
    return (ushort)r;
}

__device__ __forceinline__ float4 bf4_to_f4(uint a, uint b) {
    float4 r;
    r.x = __uint_as_float(a << 16);
    r.y = __uint_as_float(a & 0xffff0000u);
    r.z = __uint_as_float(b << 16);
    r.w = __uint_as_float(b & 0xffff0000u);
    return r;
}

__device__ __forceinline__ float4 ld_bf16x4(const uint2* p) {
    uint2 q = *p;
    return bf4_to_f4(q.x, q.y);
}

// ---- CSR build ----------------------------------------------------------

__global__ void count_edges_k(const int* __restrict__ dst, int* __restrict__ cnt, int E) {
    int e = blockIdx.x * 256 + threadIdx.x;
    if (e < E) atomicAdd(&cnt[dst[e]], 1);
}

__global__ void scan_local_k(const int* __restrict__ cnt, int* __restrict__ rowptr,
                             int* __restrict__ bsum, int n) {
    __shared__ int tmp[1024];
    int t = threadIdx.x;
    int i = blockIdx.x * 1024 + t;
    int v = (i < n) ? cnt[i] : 0;
    tmp[t] = v;
    __syncthreads();
    for (int off = 1; off < 1024; off <<= 1) {
        int a = (t >= off) ? tmp[t - off] : 0;
        __syncthreads();
        tmp[t] += a;
        __syncthreads();
    }
    if (i < n) rowptr[i] = tmp[t] - v;      // block-local exclusive scan
    if (t == 1023) bsum[blockIdx.x] = tmp[1023];
}

__global__ void scan_sums_k(int* bsum, int nb, int* rowptr, int n) {
    int t = threadIdx.x;                    // 64 threads, nb <= 64
    int v = (t < nb) ? bsum[t] : 0;
    int s = v;
#pragma unroll
    for (int o = 1; o < 64; o <<= 1) {
        int u = __shfl_up(s, o);
        if (t >= o) s += u;
    }
    if (t < nb) bsum[t] = s - v;            // exclusive
    if (t == nb - 1) rowptr[n] = s;         // total
}

__global__ void finalize_k(int* __restrict__ rowptr, const int* __restrict__ bsum,
                           const int* __restrict__ cnt, float* __restrict__ dinv,
                           int* __restrict__ cursor, int n) {
    int i = blockIdx.x * 1024 + threadIdx.x;
    if (i < n) {
        rowptr[i] += bsum[blockIdx.x];
        dinv[i] = rsqrtf((float)(cnt[i] + 1));   // +1 self loop; deg >= 1 always
        cursor[i] = 0;
    }
}

__global__ void fill_csr_k(const int* __restrict__ src, const int* __restrict__ dst,
                           const int* __restrict__ rowptr, int* __restrict__ cursor,
                           const float* __restrict__ dinv, int2* __restrict__ csr_sw, int E) {
    int e = blockIdx.x * 256 + threadIdx.x;
    if (e >= E) return;
    int s = src[e], d = dst[e];
    int p = rowptr[d] + atomicAdd(&cursor[d], 1);
    csr_sw[p] = make_int2(s, __float_as_int(dinv[s] * dinv[d]));
}

// ---- unpool scatter (f32 -> bf16 rows) ----------------------------------

__global__ void scatter_x_k(const float4* __restrict__ x4, const int* __restrict__ idx,
                            ushort4* __restrict__ c0) {
    int i = blockIdx.x * 256 + threadIdx.x;   // NP*16 quads
    if (i >= NP * 16) return;
    int row = i >> 4, q = i & 15;
    float4 v = x4[i];
    ushort4 o;
    o.x = f2bf(v.x); o.y = f2bf(v.y); o.z = f2bf(v.z); o.w = f2bf(v.w);
    c0[(size_t)idx[row] * 16 + q] = o;
}

// ---- GEMM: xw_bf16[50000x64] = cur_bf16[50000x64] @ W[64x64] ------------

__global__ void gemm64_k(const uint2* __restrict__ in2, const float* __restrict__ W,
                         ushort* __restrict__ out) {
    __shared__ float sW[64][64];     // 16 KB
    __shared__ float srow[16][64];   // 4 KB
    int t = threadIdx.x;             // 256 threads
    const float4* W4 = (const float4*)W;
    float4* sW4 = (float4*)sW;
#pragma unroll
    for (int j = 0; j < 4; ++j) sW4[t + 256 * j] = W4[t + 256 * j];
    int r0 = blockIdx.x * 16;
    float4 val = ld_bf16x4(in2 + (size_t)r0 * 16 + t);
    *(float4*)&srow[t >> 4][4 * (t & 15)] = val;
    __syncthreads();
    int r = t >> 4;            // 0..15
    int c4 = (t & 15) * 4;     // 0,4,...,60
    float ax = 0.f, ay = 0.f, az = 0.f, aw = 0.f;
#pragma unroll
    for (int k = 0; k < 64; ++k) {
        float a = srow[r][k];
        float4 w = *(const float4*)&sW[k][c4];
        ax += a * w.x; ay += a * w.y; az += a * w.z; aw += a * w.w;
    }
    ushort4 o;
    o.x = f2bf(ax); o.y = f2bf(ay); o.z = f2bf(az); o.w = f2bf(aw);
    *(ushort4*)&out[(size_t)(r0 + r) * 64 + c4] = o;
}

// ---- fused: aggregate(bf16 gather) + bias + LN + LeakyReLU --------------
// 8 nodes per wave: each 8-lane octet owns one node. Lane l8 holds features
// 8*l8..8*l8+7 (one uint4 = 8 bf16 = 16B; 8 lanes cover the 128B row).
// Edge loop 8-deep unrolled -> 64 row-gathers in flight per wave.
// If last!=0: epilogue fuses h = 0.5*(c1+c2+c3+act), writes f32 out.

__global__ void agg_ln_k(const uint4* __restrict__ xw4, const int* __restrict__ rowptr,
                         const int2* __restrict__ csr_sw, const float* __restrict__ dinv,
                         const float4* __restrict__ bias4, const float4* __restrict__ gamma4,
                         const float4* __restrict__ beta4, uint4* next,
                         const uint4* c1, const uint4* c2, const uint4* c3,
                         float4* outp, int last) {
    int tid = threadIdx.x;
    int l8 = tid & 7;                       // feature octet-chunk 0..7
    int v = blockIdx.x * 32 + (tid >> 3);   // 32 nodes per 256-thread block
    if (v >= NN) return;
    float dv = dinv[v];
    int jb = rowptr[v], je = rowptr[v + 1];
    float4 aLo, aHi;
    {
        uint4 q = xw4[(size_t)v * 8 + l8];   // self loop
        float4 lo = bf4_to_f4(q.x, q.y), hi = bf4_to_f4(q.z, q.w);
        float s = dv * dv;
        aLo.x = s * lo.x; aLo.y = s * lo.y; aLo.z = s * lo.z; aLo.w = s * lo.w;
        aHi.x = s * hi.x; aHi.y = s * hi.y; aHi.z = s * hi.z; aHi.w = s * hi.w;
    }
    for (int j = jb; j < je; j += 8) {
        int2 s0 = csr_sw[j];
        int2 s1 = csr_sw[min(j + 1, je - 1)];
        int2 s2 = csr_sw[min(j + 2, je - 1)];
        int2 s3 = csr_sw[min(j + 3, je - 1)];
        int2 s4 = csr_sw[min(j + 4, je - 1)];
        int2 s5 = csr_sw[min(j + 5, je - 1)];
        int2 s6 = csr_sw[min(j + 6, je - 1)];
        int2 s7 = csr_sw[min(j + 7, je - 1)];
        float w0 = __int_as_float(s0.y);
        float w1 = (j + 1 < je) ? __int_as_float(s1.y) : 0.f;
        float w2 = (j + 2 < je) ? __int_as_float(s2.y) : 0.f;
        float w3 = (j + 3 < je) ? __int_as_float(s3.y) : 0.f;
        float w4 = (j + 4 < je) ? __int_as_float(s4.y) : 0.f;
        float w5 = (j + 5 < je) ? __int_as_float(s5.y) : 0.f;
        float w6 = (j + 6 < je) ? __int_as_float(s6.y) : 0.f;
        float w7 = (j + 7 < je) ? __int_as_float(s7.y) : 0.f;
        uint4 q0 = xw4[(size_t)s0.x * 8 + l8];
        uint4 q1 = xw4[(size_t)s1.x * 8 + l8];
        uint4 q2 = xw4[(size_t)s2.x * 8 + l8];
        uint4 q3 = xw4[(size_t)s3.x * 8 + l8];
        uint4 q4 = xw4[(size_t)s4.x * 8 + l8];
        uint4 q5 = xw4[(size_t)s5.x * 8 + l8];
        uint4 q6 = xw4[(size_t)s6.x * 8 + l8];
        uint4 q7 = xw4[(size_t)s7.x * 8 + l8];
#define ACC(Q, W) { \
        float4 lo = bf4_to_f4(Q.x, Q.y), hi = bf4_to_f4(Q.z, Q.w); \
        aLo.x += W * lo.x; aLo.y += W * lo.y; aLo.z += W * lo.z; aLo.w += W * lo.w; \
        aHi.x += W * hi.x; aHi.y += W * hi.y; aHi.z += W * hi.z; aHi.w += W * hi.w; }
        ACC(q0, w0) ACC(q1, w1) ACC(q2, w2) ACC(q3, w3)
        ACC(q4, w4) ACC(q5, w5) ACC(q6, w6) ACC(q7, w7)
#undef ACC
    }
    float4 bLo = bias4[2 * l8], bBhi = bias4[2 * l8 + 1];
    aLo.x += bLo.x; aLo.y += bLo.y; aLo.z += bLo.z; aLo.w += bLo.w;
    aHi.x += bBhi.x; aHi.y += bBhi.y; aHi.z += bBhi.z; aHi.w += bBhi.w;
    // LayerNorm over 64 features within the 8-lane octet
    float s = aLo.x + aLo.y + aLo.z + aLo.w + aHi.x + aHi.y + aHi.z + aHi.w;
#pragma unroll
    for (int o = 1; o <= 4; o <<= 1) s += __shfl_xor(s, o);
    float mu = s * (1.0f / 64.0f);
    float4 cLo = make_float4(aLo.x - mu, aLo.y - mu, aLo.z - mu, aLo.w - mu);
    float4 cHi = make_float4(aHi.x - mu, aHi.y - mu, aHi.z - mu, aHi.w - mu);
    float q2v = cLo.x * cLo.x + cLo.y * cLo.y + cLo.z * cLo.z + cLo.w * cLo.w
              + cHi.x * cHi.x + cHi.y * cHi.y + cHi.z * cHi.z + cHi.w * cHi.w;
#pragma unroll
    for (int o = 1; o <= 4; o <<= 1) q2v += __shfl_xor(q2v, o);
    float rs = rsqrtf(q2v * (1.0f / 64.0f) + 1e-5f);
    float4 gLo = gamma4[2 * l8], gHi = gamma4[2 * l8 + 1];
    float4 tLo = beta4[2 * l8],  tHi = beta4[2 * l8 + 1];
    float4 yLo = make_float4(cLo.x * rs * gLo.x + tLo.x, cLo.y * rs * gLo.y + tLo.y,
                             cLo.z * rs * gLo.z + tLo.z, cLo.w * rs * gLo.w + tLo.w);
    float4 yHi = make_float4(cHi.x * rs * gHi.x + tHi.x, cHi.y * rs * gHi.y + tHi.y,
                             cHi.z * rs * gHi.z + tHi.z, cHi.w * rs * gHi.w + tHi.w);
    float4 eLo = make_float4(yLo.x > 0.f ? yLo.x : 0.01f * yLo.x,
                             yLo.y > 0.f ? yLo.y : 0.01f * yLo.y,
                             yLo.z > 0.f ? yLo.z : 0.01f * yLo.z,
                             yLo.w > 0.f ? yLo.w : 0.01f * yLo.w);
    float4 eHi = make_float4(yHi.x > 0.f ? yHi.x : 0.01f * yHi.x,
                             yHi.y > 0.f ? yHi.y : 0.01f * yHi.y,
                             yHi.z > 0.f ? yHi.z : 0.01f * yHi.z,
                             yHi.w > 0.f ? yHi.w : 0.01f * yHi.w);
    if (!last) {
        uint4 o;
        o.x = (uint)f2bf(eLo.x) | ((uint)f2bf(eLo.y) << 16);
        o.y = (uint)f2bf(eLo.z) | ((uint)f2bf(eLo.w) << 16);
        o.z = (uint)f2bf(eHi.x) | ((uint)f2bf(eHi.y) << 16);
        o.w = (uint)f2bf(eHi.z) | ((uint)f2bf(eHi.w) << 16);
        next[(size_t)v * 8 + l8] = o;
    } else {
        uint4 u1 = c1[(size_t)v * 8 + l8];
        uint4 u2 = c2[(size_t)v * 8 + l8];
        uint4 u3 = c3[(size_t)v * 8 + l8];
        float4 p1 = bf4_to_f4(u1.x, u1.y), p1h = bf4_to_f4(u1.z, u1.w);
        float4 p2 = bf4_to_f4(u2.x, u2.y), p2h = bf4_to_f4(u2.z, u2.w);
        float4 p3 = bf4_to_f4(u3.x, u3.y), p3h = bf4_to_f4(u3.z, u3.w);
        float4 oLo, oHi;
        oLo.x = 0.5f * (p1.x + p2.x + p3.x + eLo.x);
        oLo.y = 0.5f * (p1.y + p2.y + p3.y + eLo.y);
        oLo.z = 0.5f * (p1.z + p2.z + p3.z + eLo.z);
        oLo.w = 0.5f * (p1.w + p2.w + p3.w + eLo.w);
        oHi.x = 0.5f * (p1h.x + p2h.x + p3h.x + eHi.x);
        oHi.y = 0.5f * (p1h.y + p2h.y + p3h.y + eHi.y);
        oHi.z = 0.5f * (p1h.z + p2h.z + p3h.z + eHi.z);
        oHi.w = 0.5f * (p1h.w + p2h.w + p3h.w + eHi.w);
        outp[(size_t)v * 16 + 2 * l8]     = oLo;
        outp[(size_t)v * 16 + 2 * l8 + 1] = oHi;
    }
}

// ---- launch -------------------------------------------------------------

extern "C" void kernel_launch(void* const* d_in, const int* in_sizes, int n_in,
                              void* d_out, int out_size, void* d_ws, size_t ws_size,
                              hipStream_t stream) {
    const float* x      = (const float*)d_in[0];
    const int*   ei     = (const int*)d_in[1];
    const int*   src    = ei;
    const int*   dst    = ei + NE;
    const int*   idx    = (const int*)d_in[2];
    const float* Ws     = (const float*)d_in[3];
    const float* bs     = (const float*)d_in[4];
    const float* gammas = (const float*)d_in[5];
    const float* betas  = (const float*)d_in[6];
    float* out = (float*)d_out;

    char* w = (char*)d_ws;
    auto alloc = [&](size_t bytes) -> char* {
        char* p = w;
        w += (bytes + 255) & ~(size_t)255;
        return p;
    };
    ushort* c[NL];
    for (int l = 0; l < NL; ++l) c[l] = (ushort*)alloc((size_t)NN * 64 * 2);
    ushort* xw    = (ushort*)alloc((size_t)NN * 64 * 2);
    int*   cnt    = (int*)alloc((size_t)NN * 4);
    int*   rowptr = (int*)alloc((size_t)(NN + 1) * 4);
    int*   cursor = (int*)alloc((size_t)NN * 4);
    float* dinv   = (float*)alloc((size_t)NN * 4);
    int*   bsum   = (int*)alloc(64 * 4);
    int2*  csr_sw = (int2*)alloc((size_t)NE * 8);

    hipMemsetAsync(cnt, 0, (size_t)NN * 4, stream);
    hipMemsetAsync(c[0], 0, (size_t)NN * 64 * 2, stream);

    count_edges_k<<<(NE + 255) / 256, 256, 0, stream>>>(dst, cnt, NE);
    int nb = (NN + 1023) / 1024;   // 49
    scan_local_k<<<nb, 1024, 0, stream>>>(cnt, rowptr, bsum, NN);
    scan_sums_k<<<1, 64, 0, stream>>>(bsum, nb, rowptr, NN);
    finalize_k<<<nb, 1024, 0, stream>>>(rowptr, bsum, cnt, dinv, cursor, NN);
    fill_csr_k<<<(NE + 255) / 256, 256, 0, stream>>>(src, dst, rowptr, cursor, dinv,
                                                     csr_sw, NE);
    scatter_x_k<<<(NP * 16 + 255) / 256, 256, 0, stream>>>((const float4*)x, idx,
                                                           (ushort4*)c[0]);

    int agrid = (NN + 31) / 32;   // 1563
    for (int l = 0; l < NL; ++l) {
        gemm64_k<<<NN / 16, 256, 0, stream>>>((const uint2*)c[l], Ws + (size_t)l * 64 * 64,
                                              xw);
        int last = (l == NL - 1);
        agg_ln_k<<<agrid, 256, 0, stream>>>((const uint4*)xw, rowptr, csr_sw, dinv,
                                            (const float4*)(bs + l * 64),
                                            (const float4*)(gammas + l * 64),
                                            (const float4*)(betas + l * 64),
                                            last ? nullptr : (uint4*)c[l + 1],
                                            (const uint4*)c[1], (const uint4*)c[2],
                                            (const uint4*)c[3], (float4*)out, last);
    }
}

// Round 7
// 204.567 us; speedup vs baseline: 1.5040x; 1.1512x over previous
//
#include <hip/hip_runtime.h>
#include <hip/hip_fp16.h>

#define NN 50000
#define NP 25000
#define NE 800000
#define DD 64
#define NL 4

// ---- helpers ------------------------------------------------------------

__device__ __forceinline__ ushort f2bf(float f) {
    unsigned u = __float_as_uint(f);
    unsigned r = (u + 0x7fffu + ((u >> 16) & 1u)) >> 16;   // RNE
    return (ushort)r;
}

__device__ __forceinline__ float4 bf4_to_f4(uint a, uint b) {
    float4 r;
    r.x = __uint_as_float(a << 16);
    r.y = __uint_as_float(a & 0xffff0000u);
    r.z = __uint_as_float(b << 16);
    r.w = __uint_as_float(b & 0xffff0000u);
    return r;
}

__device__ __forceinline__ float4 ld_bf16x4(const uint2* p) {
    uint2 q = *p;
    return bf4_to_f4(q.x, q.y);
}

// ---- CSR build ----------------------------------------------------------
// Pass 1: count in-degree AND record each edge's rank within its dst bucket
// (the atomicAdd return). Pass 2 (fill) then needs NO atomics.

__global__ void count_edges_k(const int* __restrict__ dst, int* __restrict__ cnt,
                              int* __restrict__ rank, int E) {
    int e = blockIdx.x * 256 + threadIdx.x;
    if (e < E) rank[e] = atomicAdd(&cnt[dst[e]], 1);
}

__global__ void scan_local_k(const int* __restrict__ cnt, int* __restrict__ rowptr,
                             int* __restrict__ bsum, int n) {
    __shared__ int tmp[1024];
    int t = threadIdx.x;
    int i = blockIdx.x * 1024 + t;
    int v = (i < n) ? cnt[i] : 0;
    tmp[t] = v;
    __syncthreads();
    for (int off = 1; off < 1024; off <<= 1) {
        int a = (t >= off) ? tmp[t - off] : 0;
        __syncthreads();
        tmp[t] += a;
        __syncthreads();
    }
    if (i < n) rowptr[i] = tmp[t] - v;      // block-local exclusive scan
    if (t == 1023) bsum[blockIdx.x] = tmp[1023];
}

__global__ void scan_sums_k(int* bsum, int nb, int* rowptr, int n) {
    int t = threadIdx.x;                    // 64 threads, nb <= 64
    int v = (t < nb) ? bsum[t] : 0;
    int s = v;
#pragma unroll
    for (int o = 1; o < 64; o <<= 1) {
        int u = __shfl_up(s, o);
        if (t >= o) s += u;
    }
    if (t < nb) bsum[t] = s - v;            // exclusive
    if (t == nb - 1) rowptr[n] = s;         // total
}

__global__ void finalize_k(int* __restrict__ rowptr, const int* __restrict__ bsum,
                           const int* __restrict__ cnt, float* __restrict__ dinv, int n) {
    int i = blockIdx.x * 1024 + threadIdx.x;
    if (i < n) {
        rowptr[i] += bsum[blockIdx.x];
        dinv[i] = rsqrtf((float)(cnt[i] + 1));   // +1 self loop; deg >= 1 always
    }
}

// csr entry: bits 0..15 = src index (NN < 65536), bits 16..31 = fp16 weight.
__global__ void fill_csr_k(const int* __restrict__ src, const int* __restrict__ dst,
                           const int* __restrict__ rank, const int* __restrict__ rowptr,
                           const float* __restrict__ dinv, uint* __restrict__ csr, int E) {
    int e = blockIdx.x * 256 + threadIdx.x;
    if (e >= E) return;
    int s = src[e], d = dst[e];
    int p = rowptr[d] + rank[e];
    float w = dinv[s] * dinv[d];
    uint h = (uint)__half_as_ushort(__float2half_rn(w));
    csr[p] = (uint)s | (h << 16);
}

// ---- unpool scatter (f32 -> bf16 rows) ----------------------------------

__global__ void scatter_x_k(const float4* __restrict__ x4, const int* __restrict__ idx,
                            ushort4* __restrict__ c0) {
    int i = blockIdx.x * 256 + threadIdx.x;   // NP*16 quads
    if (i >= NP * 16) return;
    int row = i >> 4, q = i & 15;
    float4 v = x4[i];
    ushort4 o;
    o.x = f2bf(v.x); o.y = f2bf(v.y); o.z = f2bf(v.z); o.w = f2bf(v.w);
    c0[(size_t)idx[row] * 16 + q] = o;
}

// ---- GEMM: xw_bf16[50000x64] = cur_bf16[50000x64] @ W[64x64] ------------

__global__ void gemm64_k(const uint2* __restrict__ in2, const float* __restrict__ W,
                         ushort* __restrict__ out) {
    __shared__ float sW[64][64];     // 16 KB
    __shared__ float srow[16][64];   // 4 KB
    int t = threadIdx.x;             // 256 threads
    const float4* W4 = (const float4*)W;
    float4* sW4 = (float4*)sW;
#pragma unroll
    for (int j = 0; j < 4; ++j) sW4[t + 256 * j] = W4[t + 256 * j];
    int r0 = blockIdx.x * 16;
    float4 val = ld_bf16x4(in2 + (size_t)r0 * 16 + t);
    *(float4*)&srow[t >> 4][4 * (t & 15)] = val;
    __syncthreads();
    int r = t >> 4;            // 0..15
    int c4 = (t & 15) * 4;     // 0,4,...,60
    float ax = 0.f, ay = 0.f, az = 0.f, aw = 0.f;
#pragma unroll
    for (int k = 0; k < 64; ++k) {
        float a = srow[r][k];
        float4 w = *(const float4*)&sW[k][c4];
        ax += a * w.x; ay += a * w.y; az += a * w.z; aw += a * w.w;
    }
    ushort4 o;
    o.x = f2bf(ax); o.y = f2bf(ay); o.z = f2bf(az); o.w = f2bf(aw);
    *(ushort4*)&out[(size_t)(r0 + r) * 64 + c4] = o;
}

// ---- fused: aggregate(bf16 gather) + bias + LN + LeakyReLU --------------
// 8 nodes per wave: each 8-lane octet owns one node. Lane l8 holds features
// 8*l8..8*l8+7 (one uint4 = 8 bf16 = 16B; 8 lanes cover the 128B row).
// Edge loop 8-deep unrolled -> 64 row-gathers in flight per wave.
// If last!=0: epilogue fuses h = 0.5*(c1+c2+c3+act), writes f32 out.

__global__ void agg_ln_k(const uint4* __restrict__ xw4, const int* __restrict__ rowptr,
                         const uint* __restrict__ csr, const float* __restrict__ dinv,
                         const float4* __restrict__ bias4, const float4* __restrict__ gamma4,
                         const float4* __restrict__ beta4, uint4* next,
                         const uint4* c1, const uint4* c2, const uint4* c3,
                         float4* outp, int last) {
    int tid = threadIdx.x;
    int l8 = tid & 7;                       // feature octet-chunk 0..7
    int v = blockIdx.x * 32 + (tid >> 3);   // 32 nodes per 256-thread block
    if (v >= NN) return;
    float dv = dinv[v];
    int jb = rowptr[v], je = rowptr[v + 1];
    float4 aLo, aHi;
    {
        uint4 q = xw4[(size_t)v * 8 + l8];   // self loop
        float4 lo = bf4_to_f4(q.x, q.y), hi = bf4_to_f4(q.z, q.w);
        float s = dv * dv;
        aLo.x = s * lo.x; aLo.y = s * lo.y; aLo.z = s * lo.z; aLo.w = s * lo.w;
        aHi.x = s * hi.x; aHi.y = s * hi.y; aHi.z = s * hi.z; aHi.w = s * hi.w;
    }
#define UNPK(E) ((int)((E) & 0xffffu))
#define WGT(E)  __half2float(__ushort_as_half((ushort)((E) >> 16)))
    for (int j = jb; j < je; j += 8) {
        uint e0 = csr[j];
        uint e1 = csr[min(j + 1, je - 1)];
        uint e2 = csr[min(j + 2, je - 1)];
        uint e3 = csr[min(j + 3, je - 1)];
        uint e4 = csr[min(j + 4, je - 1)];
        uint e5 = csr[min(j + 5, je - 1)];
        uint e6 = csr[min(j + 6, je - 1)];
        uint e7 = csr[min(j + 7, je - 1)];
        float w0 = WGT(e0);
        float w1 = (j + 1 < je) ? WGT(e1) : 0.f;
        float w2 = (j + 2 < je) ? WGT(e2) : 0.f;
        float w3 = (j + 3 < je) ? WGT(e3) : 0.f;
        float w4 = (j + 4 < je) ? WGT(e4) : 0.f;
        float w5 = (j + 5 < je) ? WGT(e5) : 0.f;
        float w6 = (j + 6 < je) ? WGT(e6) : 0.f;
        float w7 = (j + 7 < je) ? WGT(e7) : 0.f;
        uint4 q0 = xw4[(size_t)UNPK(e0) * 8 + l8];
        uint4 q1 = xw4[(size_t)UNPK(e1) * 8 + l8];
        uint4 q2 = xw4[(size_t)UNPK(e2) * 8 + l8];
        uint4 q3 = xw4[(size_t)UNPK(e3) * 8 + l8];
        uint4 q4 = xw4[(size_t)UNPK(e4) * 8 + l8];
        uint4 q5 = xw4[(size_t)UNPK(e5) * 8 + l8];
        uint4 q6 = xw4[(size_t)UNPK(e6) * 8 + l8];
        uint4 q7 = xw4[(size_t)UNPK(e7) * 8 + l8];
#define ACC(Q, W) { \
        float4 lo = bf4_to_f4(Q.x, Q.y), hi = bf4_to_f4(Q.z, Q.w); \
        aLo.x += W * lo.x; aLo.y += W * lo.y; aLo.z += W * lo.z; aLo.w += W * lo.w; \
        aHi.x += W * hi.x; aHi.y += W * hi.y; aHi.z += W * hi.z; aHi.w += W * hi.w; }
        ACC(q0, w0) ACC(q1, w1) ACC(q2, w2) ACC(q3, w3)
        ACC(q4, w4) ACC(q5, w5) ACC(q6, w6) ACC(q7, w7)
#undef ACC
    }
#undef UNPK
#undef WGT
    float4 bLo = bias4[2 * l8], bBhi = bias4[2 * l8 + 1];
    aLo.x += bLo.x; aLo.y += bLo.y; aLo.z += bLo.z; aLo.w += bLo.w;
    aHi.x += bBhi.x; aHi.y += bBhi.y; aHi.z += bBhi.z; aHi.w += bBhi.w;
    // LayerNorm over 64 features within the 8-lane octet
    float s = aLo.x + aLo.y + aLo.z + aLo.w + aHi.x + aHi.y + aHi.z + aHi.w;
#pragma unroll
    for (int o = 1; o <= 4; o <<= 1) s += __shfl_xor(s, o);
    float mu = s * (1.0f / 64.0f);
    float4 cLo = make_float4(aLo.x - mu, aLo.y - mu, aLo.z - mu, aLo.w - mu);
    float4 cHi = make_float4(aHi.x - mu, aHi.y - mu, aHi.z - mu, aHi.w - mu);
    float q2v = cLo.x * cLo.x + cLo.y * cLo.y + cLo.z * cLo.z + cLo.w * cLo.w
              + cHi.x * cHi.x + cHi.y * cHi.y + cHi.z * cHi.z + cHi.w * cHi.w;
#pragma unroll
    for (int o = 1; o <= 4; o <<= 1) q2v += __shfl_xor(q2v, o);
    float rs = rsqrtf(q2v * (1.0f / 64.0f) + 1e-5f);
    float4 gLo = gamma4[2 * l8], gHi = gamma4[2 * l8 + 1];
    float4 tLo = beta4[2 * l8],  tHi = beta4[2 * l8 + 1];
    float4 yLo = make_float4(cLo.x * rs * gLo.x + tLo.x, cLo.y * rs * gLo.y + tLo.y,
                             cLo.z * rs * gLo.z + tLo.z, cLo.w * rs * gLo.w + tLo.w);
    float4 yHi = make_float4(cHi.x * rs * gHi.x + tHi.x, cHi.y * rs * gHi.y + tHi.y,
                             cHi.z * rs * gHi.z + tHi.z, cHi.w * rs * gHi.w + tHi.w);
    float4 eLo = make_float4(yLo.x > 0.f ? yLo.x : 0.01f * yLo.x,
                             yLo.y > 0.f ? yLo.y : 0.01f * yLo.y,
                             yLo.z > 0.f ? yLo.z : 0.01f * yLo.z,
                             yLo.w > 0.f ? yLo.w : 0.01f * yLo.w);
    float4 eHi = make_float4(yHi.x > 0.f ? yHi.x : 0.01f * yHi.x,
                             yHi.y > 0.f ? yHi.y : 0.01f * yHi.y,
                             yHi.z > 0.f ? yHi.z : 0.01f * yHi.z,
                             yHi.w > 0.f ? yHi.w : 0.01f * yHi.w);
    if (!last) {
        uint4 o;
        o.x = (uint)f2bf(eLo.x) | ((uint)f2bf(eLo.y) << 16);
        o.y = (uint)f2bf(eLo.z) | ((uint)f2bf(eLo.w) << 16);
        o.z = (uint)f2bf(eHi.x) | ((uint)f2bf(eHi.y) << 16);
        o.w = (uint)f2bf(eHi.z) | ((uint)f2bf(eHi.w) << 16);
        next[(size_t)v * 8 + l8] = o;
    } else {
        uint4 u1 = c1[(size_t)v * 8 + l8];
        uint4 u2 = c2[(size_t)v * 8 + l8];
        uint4 u3 = c3[(size_t)v * 8 + l8];
        float4 p1 = bf4_to_f4(u1.x, u1.y), p1h = bf4_to_f4(u1.z, u1.w);
        float4 p2 = bf4_to_f4(u2.x, u2.y), p2h = bf4_to_f4(u2.z, u2.w);
        float4 p3 = bf4_to_f4(u3.x, u3.y), p3h = bf4_to_f4(u3.z, u3.w);
        float4 oLo, oHi;
        oLo.x = 0.5f * (p1.x + p2.x + p3.x + eLo.x);
        oLo.y = 0.5f * (p1.y + p2.y + p3.y + eLo.y);
        oLo.z = 0.5f * (p1.z + p2.z + p3.z + eLo.z);
        oLo.w = 0.5f * (p1.w + p2.w + p3.w + eLo.w);
        oHi.x = 0.5f * (p1h.x + p2h.x + p3h.x + eHi.x);
        oHi.y = 0.5f * (p1h.y + p2h.y + p3h.y + eHi.y);
        oHi.z = 0.5f * (p1h.z + p2h.z + p3h.z + eHi.z);
        oHi.w = 0.5f * (p1h.w + p2h.w + p3h.w + eHi.w);
        outp[(size_t)v * 16 + 2 * l8]     = oLo;
        outp[(size_t)v * 16 + 2 * l8 + 1] = oHi;
    }
}

// ---- launch -------------------------------------------------------------

extern "C" void kernel_launch(void* const* d_in, const int* in_sizes, int n_in,
                              void* d_out, int out_size, void* d_ws, size_t ws_size,
                              hipStream_t stream) {
    const float* x      = (const float*)d_in[0];
    const int*   ei     = (const int*)d_in[1];
    const int*   src    = ei;
    const int*   dst    = ei + NE;
    const int*   idx    = (const int*)d_in[2];
    const float* Ws     = (const float*)d_in[3];
    const float* bs     = (const float*)d_in[4];
    const float* gammas = (const float*)d_in[5];
    const float* betas  = (const float*)d_in[6];
    float* out = (float*)d_out;

    char* w = (char*)d_ws;
    auto alloc = [&](size_t bytes) -> char* {
        char* p = w;
        w += (bytes + 255) & ~(size_t)255;
        return p;
    };
    ushort* c[NL];
    for (int l = 0; l < NL; ++l) c[l] = (ushort*)alloc((size_t)NN * 64 * 2);
    ushort* xw    = (ushort*)alloc((size_t)NN * 64 * 2);
    int*   cnt    = (int*)alloc((size_t)NN * 4);
    int*   rowptr = (int*)alloc((size_t)(NN + 1) * 4);
    int*   rank   = (int*)alloc((size_t)NE * 4);
    float* dinv   = (float*)alloc((size_t)NN * 4);
    int*   bsum   = (int*)alloc(64 * 4);
    uint*  csr    = (uint*)alloc((size_t)NE * 4);

    hipMemsetAsync(cnt, 0, (size_t)NN * 4, stream);
    hipMemsetAsync(c[0], 0, (size_t)NN * 64 * 2, stream);

    count_edges_k<<<(NE + 255) / 256, 256, 0, stream>>>(dst, cnt, rank, NE);
    int nb = (NN + 1023) / 1024;   // 49
    scan_local_k<<<nb, 1024, 0, stream>>>(cnt, rowptr, bsum, NN);
    scan_sums_k<<<1, 64, 0, stream>>>(bsum, nb, rowptr, NN);
    finalize_k<<<nb, 1024, 0, stream>>>(rowptr, bsum, cnt, dinv, NN);
    fill_csr_k<<<(NE + 255) / 256, 256, 0, stream>>>(src, dst, rank, rowptr, dinv,
                                                     csr, NE);
    scatter_x_k<<<(NP * 16 + 255) / 256, 256, 0, stream>>>((const float4*)x, idx,
                                                           (ushort4*)c[0]);

    int agrid = (NN + 31) / 32;   // 1563
    for (int l = 0; l < NL; ++l) {
        gemm64_k<<<NN / 16, 256, 0, stream>>>((const uint2*)c[l], Ws + (size_t)l * 64 * 64,
                                              xw);
        int last = (l == NL - 1);
        agg_ln_k<<<agrid, 256, 0, stream>>>((const uint4*)xw, rowptr, csr, dinv,
                                            (const float4*)(bs + l * 64),
                                            (const float4*)(gammas + l * 64),
                                            (const float4*)(betas + l * 64),
                                            last ? nullptr : (uint4*)c[l + 1],
                                            (const uint4*)c[1], (const uint4*)c[2],
                                            (const uint4*)c[3], (float4*)out, last);
    }
}